// Round 2
// baseline (311.944 us; speedup 1.0000x reference)
//
#include <hip/hip_runtime.h>
#include <math.h>

#define Bsz 128
#define Usz 16
#define Dsz 256
#define Nsz 1024
#define Osz 256

// ---------------- lr = softmax_u(X·alr / T) ----------------
// grid = B, block = 256 (16 u-groups x 16 lanes)
__global__ __launch_bounds__(256)
void lr_kernel(const float* __restrict__ X, const float* __restrict__ alr,
               const float* __restrict__ temp, float* __restrict__ lr)
{
    const int b = blockIdx.x;
    const int t = threadIdx.x;
    const int u = t >> 4;
    const int l = t & 15;
    const float* xp = X + ((size_t)b * Usz + u) * Dsz;
    const float* ap = alr + (size_t)u * Dsz;
    float s = 0.f;
    for (int d = l; d < Dsz; d += 16) s += xp[d] * ap[d];
    s += __shfl_down(s, 8, 16);
    s += __shfl_down(s, 4, 16);
    s += __shfl_down(s, 2, 16);
    s += __shfl_down(s, 1, 16);
    __shared__ float logits[16];
    if (l == 0) logits[u] = s;
    __syncthreads();
    if (t < 16) {
        const float T = temp[0];
        float m = -1e30f;
        #pragma unroll
        for (int i = 0; i < 16; i++) m = fmaxf(m, logits[i] / T);
        float sum = 0.f;
        #pragma unroll
        for (int i = 0; i < 16; i++) sum += expf(logits[i] / T - m);
        lr[(size_t)b * Usz + t] = expf(logits[t] / T - m) / sum;
    }
}

// ---------------- new_state = (1-lr)*s + lr*tanh(X·Win + (s*sr)·W + bias) ----
// grid = (N/64, B/64, U), block = 256, 64x64 tile, 4x4 per thread
__global__ __launch_bounds__(256)
void state_kernel(const float* __restrict__ X, const float* __restrict__ state,
                  const float* __restrict__ W, const float* __restrict__ Win,
                  const float* __restrict__ bias, const float* __restrict__ sr,
                  const float* __restrict__ lr, float* __restrict__ outs)
{
    const int nt = blockIdx.x;
    const int bt = blockIdx.y;
    const int u  = blockIdx.z;
    const int t  = threadIdx.x;
    const int tx = t & 15, ty = t >> 4;

    __shared__ float As[64][17];   // +1 pad: column reads conflict-free
    __shared__ float Bs[16][64];

    float acc[4][4];
    #pragma unroll
    for (int i = 0; i < 4; i++)
        #pragma unroll
        for (int j = 0; j < 4; j++) acc[i][j] = 0.f;

    const int arow = t >> 2;          // 0..63
    const int ak0  = (t & 3) * 4;     // 0,4,8,12
    const int bkk  = t >> 4;          // 0..15
    const int bn0  = (t & 15) * 4;    // 0..60

    const float sru = sr[u];

    // ---- phase 1: feed = X(64xD) * Win(DxN) ----
    {
        const float* Ag = X   + ((size_t)(bt * 64 + arow) * Usz + u) * Dsz + ak0;
        const float* Bg = Win + ((size_t)u * Dsz + bkk) * Nsz + nt * 64 + bn0;
        for (int kb = 0; kb < Dsz; kb += 16) {
            const float4 av = *(const float4*)(Ag + kb);
            const float4 bv = *(const float4*)(Bg + (size_t)kb * Nsz);
            As[arow][ak0 + 0] = av.x; As[arow][ak0 + 1] = av.y;
            As[arow][ak0 + 2] = av.z; As[arow][ak0 + 3] = av.w;
            *(float4*)&Bs[bkk][bn0] = bv;
            __syncthreads();
            #pragma unroll
            for (int kk = 0; kk < 16; kk++) {
                const float a0 = As[ty * 4 + 0][kk];
                const float a1 = As[ty * 4 + 1][kk];
                const float a2 = As[ty * 4 + 2][kk];
                const float a3 = As[ty * 4 + 3][kk];
                const float4 b4 = *(const float4*)&Bs[kk][tx * 4];
                acc[0][0] += a0 * b4.x; acc[0][1] += a0 * b4.y; acc[0][2] += a0 * b4.z; acc[0][3] += a0 * b4.w;
                acc[1][0] += a1 * b4.x; acc[1][1] += a1 * b4.y; acc[1][2] += a1 * b4.z; acc[1][3] += a1 * b4.w;
                acc[2][0] += a2 * b4.x; acc[2][1] += a2 * b4.y; acc[2][2] += a2 * b4.z; acc[2][3] += a2 * b4.w;
                acc[3][0] += a3 * b4.x; acc[3][1] += a3 * b4.y; acc[3][2] += a3 * b4.z; acc[3][3] += a3 * b4.w;
            }
            __syncthreads();
        }
    }
    // ---- phase 2: echo = (s*sr)(64xN) * W(NxN) ----
    {
        const float* Ag = state + ((size_t)(bt * 64 + arow) * Usz + u) * Nsz + ak0;
        const float* Bg = W     + ((size_t)u * Nsz + bkk) * Nsz + nt * 64 + bn0;
        for (int kb = 0; kb < Nsz; kb += 16) {
            const float4 av = *(const float4*)(Ag + kb);
            const float4 bv = *(const float4*)(Bg + (size_t)kb * Nsz);
            As[arow][ak0 + 0] = av.x * sru; As[arow][ak0 + 1] = av.y * sru;
            As[arow][ak0 + 2] = av.z * sru; As[arow][ak0 + 3] = av.w * sru;
            *(float4*)&Bs[bkk][bn0] = bv;
            __syncthreads();
            #pragma unroll
            for (int kk = 0; kk < 16; kk++) {
                const float a0 = As[ty * 4 + 0][kk];
                const float a1 = As[ty * 4 + 1][kk];
                const float a2 = As[ty * 4 + 2][kk];
                const float a3 = As[ty * 4 + 3][kk];
                const float4 b4 = *(const float4*)&Bs[kk][tx * 4];
                acc[0][0] += a0 * b4.x; acc[0][1] += a0 * b4.y; acc[0][2] += a0 * b4.z; acc[0][3] += a0 * b4.w;
                acc[1][0] += a1 * b4.x; acc[1][1] += a1 * b4.y; acc[1][2] += a1 * b4.z; acc[1][3] += a1 * b4.w;
                acc[2][0] += a2 * b4.x; acc[2][1] += a2 * b4.y; acc[2][2] += a2 * b4.z; acc[2][3] += a2 * b4.w;
                acc[3][0] += a3 * b4.x; acc[3][1] += a3 * b4.y; acc[3][2] += a3 * b4.z; acc[3][3] += a3 * b4.w;
            }
            __syncthreads();
        }
    }
    // ---- epilogue ----
    float lrv[4];
    #pragma unroll
    for (int i = 0; i < 4; i++)
        lrv[i] = lr[(size_t)(bt * 64 + ty * 4 + i) * Usz + u];
    #pragma unroll
    for (int i = 0; i < 4; i++) {
        const int gb = bt * 64 + ty * 4 + i;
        const size_t rowbase = ((size_t)gb * Usz + u) * Nsz + nt * 64 + tx * 4;
        const float4 sv4 = *(const float4*)(state + rowbase);
        const float4 bi4 = *(const float4*)(bias + u * Nsz + nt * 64 + tx * 4);
        float4 o;
        o.x = (1.f - lrv[i]) * sv4.x + lrv[i] * tanhf(acc[i][0] + bi4.x);
        o.y = (1.f - lrv[i]) * sv4.y + lrv[i] * tanhf(acc[i][1] + bi4.y);
        o.z = (1.f - lrv[i]) * sv4.z + lrv[i] * tanhf(acc[i][2] + bi4.z);
        o.w = (1.f - lrv[i]) * sv4.w + lrv[i] * tanhf(acc[i][3] + bi4.w);
        *(float4*)(outs + rowbase) = o;
    }
}

// ---------------- output = ns(64xN) * Wout(NxO) ----------------
// grid = (O/64, B/64, U)
__global__ __launch_bounds__(256)
void out_kernel(const float* __restrict__ ns, const float* __restrict__ Wout,
                float* __restrict__ out1)
{
    const int ot = blockIdx.x;
    const int bt = blockIdx.y;
    const int u  = blockIdx.z;
    const int t  = threadIdx.x;
    const int tx = t & 15, ty = t >> 4;

    __shared__ float As[64][17];
    __shared__ float Bs[16][64];

    float acc[4][4];
    #pragma unroll
    for (int i = 0; i < 4; i++)
        #pragma unroll
        for (int j = 0; j < 4; j++) acc[i][j] = 0.f;

    const int arow = t >> 2;
    const int ak0  = (t & 3) * 4;
    const int bkk  = t >> 4;
    const int bn0  = (t & 15) * 4;

    const float* Ag = ns   + ((size_t)(bt * 64 + arow) * Usz + u) * Nsz + ak0;
    const float* Bg = Wout + ((size_t)u * Nsz + bkk) * Osz + ot * 64 + bn0;
    for (int kb = 0; kb < Nsz; kb += 16) {
        const float4 av = *(const float4*)(Ag + kb);
        const float4 bv = *(const float4*)(Bg + (size_t)kb * Osz);
        As[arow][ak0 + 0] = av.x; As[arow][ak0 + 1] = av.y;
        As[arow][ak0 + 2] = av.z; As[arow][ak0 + 3] = av.w;
        *(float4*)&Bs[bkk][bn0] = bv;
        __syncthreads();
        #pragma unroll
        for (int kk = 0; kk < 16; kk++) {
            const float a0 = As[ty * 4 + 0][kk];
            const float a1 = As[ty * 4 + 1][kk];
            const float a2 = As[ty * 4 + 2][kk];
            const float a3 = As[ty * 4 + 3][kk];
            const float4 b4 = *(const float4*)&Bs[kk][tx * 4];
            acc[0][0] += a0 * b4.x; acc[0][1] += a0 * b4.y; acc[0][2] += a0 * b4.z; acc[0][3] += a0 * b4.w;
            acc[1][0] += a1 * b4.x; acc[1][1] += a1 * b4.y; acc[1][2] += a1 * b4.z; acc[1][3] += a1 * b4.w;
            acc[2][0] += a2 * b4.x; acc[2][1] += a2 * b4.y; acc[2][2] += a2 * b4.z; acc[2][3] += a2 * b4.w;
            acc[3][0] += a3 * b4.x; acc[3][1] += a3 * b4.y; acc[3][2] += a3 * b4.z; acc[3][3] += a3 * b4.w;
        }
        __syncthreads();
    }
    #pragma unroll
    for (int i = 0; i < 4; i++) {
        const int gb = bt * 64 + ty * 4 + i;
        const size_t rowbase = ((size_t)gb * Usz + u) * Osz + ot * 64 + tx * 4;
        float4 o;
        o.x = acc[i][0]; o.y = acc[i][1]; o.z = acc[i][2]; o.w = acc[i][3];
        *(float4*)(out1 + rowbase) = o;
    }
}

extern "C" void kernel_launch(void* const* d_in, const int* in_sizes, int n_in,
                              void* d_out, int out_size, void* d_ws, size_t ws_size,
                              hipStream_t stream)
{
    (void)in_sizes; (void)n_in; (void)out_size; (void)ws_size;
    const float* X     = (const float*)d_in[0];
    const float* state = (const float*)d_in[1];
    const float* W     = (const float*)d_in[2];
    const float* Win   = (const float*)d_in[3];
    const float* bias  = (const float*)d_in[4];
    const float* Wout  = (const float*)d_in[5];
    const float* sr    = (const float*)d_in[6];
    const float* alr   = (const float*)d_in[7];
    const float* temp  = (const float*)d_in[8];

    float* out0 = (float*)d_out;                              // (B,U,N)
    float* out1 = out0 + (size_t)Bsz * Usz * Nsz;             // (B,U,O)
    float* lr   = (float*)d_ws;                               // (B,U) f32, 8 KB

    lr_kernel<<<Bsz, 256, 0, stream>>>(X, alr, temp, lr);

    dim3 g1(Nsz / 64, Bsz / 64, Usz);
    state_kernel<<<g1, 256, 0, stream>>>(X, state, W, Win, bias, sr, lr, out0);

    dim3 g2(Osz / 64, Bsz / 64, Usz);
    out_kernel<<<g2, 256, 0, stream>>>(out0, Wout, out1);
}

// Round 3
// 202.873 us; speedup vs baseline: 1.5376x; 1.5376x over previous
//
#include <hip/hip_runtime.h>
#include <math.h>

#define Bsz 128
#define Usz 16
#define Dsz 256
#define Nsz 1024
#define Osz 256

typedef __attribute__((ext_vector_type(4))) float f32x4;
typedef __attribute__((ext_vector_type(8))) short bf16x8;

__device__ __forceinline__ unsigned short f2bf(float f) {
    union { float f; unsigned int u; } v; v.f = f;
    unsigned int lsb = (v.u >> 16) & 1u;
    v.u += 0x7fffu + lsb;   // RTE
    return (unsigned short)(v.u >> 16);
}

__device__ __forceinline__ bf16x8 pack8(const float* x, float s) {
    union { bf16x8 v; unsigned short h[8]; } r;
    #pragma unroll
    for (int i = 0; i < 8; i++) r.h[i] = f2bf(x[i] * s);
    return r.v;
}

// ---------------- lr = softmax_u(X·alr / T) ----------------
__global__ __launch_bounds__(256)
void lr_kernel(const float* __restrict__ X, const float* __restrict__ alr,
               const float* __restrict__ temp, float* __restrict__ lr)
{
    const int b = blockIdx.x;
    const int t = threadIdx.x;
    const int u = t >> 4;
    const int l = t & 15;
    const float* xp = X + ((size_t)b * Usz + u) * Dsz;
    const float* ap = alr + (size_t)u * Dsz;
    float s = 0.f;
    for (int d = l; d < Dsz; d += 16) s += xp[d] * ap[d];
    s += __shfl_down(s, 8, 16);
    s += __shfl_down(s, 4, 16);
    s += __shfl_down(s, 2, 16);
    s += __shfl_down(s, 1, 16);
    __shared__ float logits[16];
    if (l == 0) logits[u] = s;
    __syncthreads();
    if (t < 16) {
        const float T = temp[0];
        float m = -1e30f;
        #pragma unroll
        for (int i = 0; i < 16; i++) m = fmaxf(m, logits[i] / T);
        float sum = 0.f;
        #pragma unroll
        for (int i = 0; i < 16; i++) sum += expf(logits[i] / T - m);
        lr[(size_t)b * Usz + t] = expf(logits[t] / T - m) / sum;
    }
}

// ---- state: C = [X | state*sr] · [Win ; W] (K=1280), then tanh/lr blend ----
// grid 512: mt = id>>8 (siblings 256 apart -> co-resident on same CU -> W L2/L1 reuse)
// XCD swizzle: id%8 == u&7 so blocks sharing A[u]/W[u] cluster per XCD.
// block tile 64m x 64n, 4 waves of 32x32 (2x2 16x16 frags), K-step 32.
__global__ __launch_bounds__(256)
void state_mfma(const float* __restrict__ X, const float* __restrict__ state,
                const float* __restrict__ W, const float* __restrict__ Win,
                const float* __restrict__ bias, const float* __restrict__ sr,
                const float* __restrict__ lr, float* __restrict__ out0)
{
    const int id = blockIdx.x;
    const int mt = id >> 8;
    const int rr = id & 255;
    const int u  = (rr & 7) | ((rr >> 7) << 3);
    const int nt = (rr >> 3) & 15;

    const int tid  = threadIdx.x;
    const int wave = tid >> 6, lane = tid & 63;
    const int l16  = lane & 15, kgl = lane >> 4;
    const int wrow = (wave & 1) * 32, wcol = (wave >> 1) * 32;

    // frag-cell layout: [blk16][kg4][idx16][8 bf16] -> 16B cells
    __shared__ __align__(16) unsigned short As[64 * 32];
    __shared__ __align__(16) unsigned short Bs[64 * 32];

    f32x4 acc[2][2] = {};

    const int sm  = tid & 63;   // A row / B col within tile
    const int skg = tid >> 6;   // k-group 0..3
    const float sru = sr[u];

    const float* Af = X     + ((size_t)(mt * 64 + sm) * Usz + u) * Dsz + skg * 8;
    const float* Ae = state + ((size_t)(mt * 64 + sm) * Usz + u) * Nsz + skg * 8;
    const float* Bf = Win + (size_t)u * Dsz * Nsz + (size_t)(skg * 8) * Nsz + nt * 64 + sm;
    const float* Be = W   + (size_t)u * Nsz * Nsz + (size_t)(skg * 8) * Nsz + nt * 64 + sm;

    float areg[8], breg[8];

    auto loadA = [&](int kb) {
        const float* p = (kb < Dsz) ? (Af + kb) : (Ae + (kb - Dsz));
        const f32x4 v0 = *(const f32x4*)p;
        const f32x4 v1 = *(const f32x4*)(p + 4);
        #pragma unroll
        for (int i = 0; i < 4; i++) { areg[i] = v0[i]; areg[4 + i] = v1[i]; }
    };
    auto loadB = [&](int kb) {
        const float* p = (kb < Dsz) ? (Bf + (size_t)kb * Nsz)
                                    : (Be + (size_t)(kb - Dsz) * Nsz);
        #pragma unroll
        for (int j = 0; j < 8; j++) breg[j] = p[(size_t)j * Nsz];
    };

    loadA(0); loadB(0);
    const int wr_off = ((sm >> 4) * 4 + skg) * 128 + (sm & 15) * 8;

    for (int step = 0; step < 40; ++step) {
        const int kb = step * 32;
        const float asc = (kb < Dsz) ? 1.f : sru;   // fold sr into echo A
        const bf16x8 av = pack8(areg, asc);
        const bf16x8 bv = pack8(breg, 1.f);
        __syncthreads();
        *(bf16x8*)&As[wr_off] = av;
        *(bf16x8*)&Bs[wr_off] = bv;
        __syncthreads();
        if (step + 1 < 40) { loadA(kb + 32); loadB(kb + 32); }  // pipeline next K-step
        bf16x8 afr[2], bfr[2];
        #pragma unroll
        for (int mi = 0; mi < 2; mi++)
            afr[mi] = *(const bf16x8*)&As[((((wrow >> 4) + mi) * 4 + kgl) * 16 + l16) * 8];
        #pragma unroll
        for (int ni = 0; ni < 2; ni++)
            bfr[ni] = *(const bf16x8*)&Bs[((((wcol >> 4) + ni) * 4 + kgl) * 16 + l16) * 8];
        #pragma unroll
        for (int mi = 0; mi < 2; mi++)
            #pragma unroll
            for (int ni = 0; ni < 2; ni++)
                acc[mi][ni] = __builtin_amdgcn_mfma_f32_16x16x32_bf16(afr[mi], bfr[ni], acc[mi][ni], 0, 0, 0);
    }

    // epilogue: C/D layout col=lane&15, row=(lane>>4)*4+reg (HW-verified)
    #pragma unroll
    for (int mi = 0; mi < 2; mi++) {
        #pragma unroll
        for (int ni = 0; ni < 2; ni++) {
            const int gcol = nt * 64 + wcol + ni * 16 + l16;
            const float bi = bias[u * Nsz + gcol];
            #pragma unroll
            for (int rg = 0; rg < 4; rg++) {
                const int grow = mt * 64 + wrow + mi * 16 + kgl * 4 + rg;
                const size_t idx = ((size_t)grow * Usz + u) * Nsz + gcol;
                const float th = tanhf(acc[mi][ni][rg] + bi);
                const float sv = state[idx];
                const float lv = lr[grow * Usz + u];
                out0[idx] = (1.f - lv) * sv + lv * th;
            }
        }
    }
}

// ---------------- out1 = ns · Wout, tile 32m x 64n ----------------
__global__ __launch_bounds__(256)
void out_mfma(const float* __restrict__ ns, const float* __restrict__ Wout,
              float* __restrict__ out1)
{
    const int id = blockIdx.x;   // 256
    const int u  = (id & 7) | ((id >> 7) << 3);
    const int mt = (id >> 3) & 3;
    const int ot = (id >> 5) & 3;

    const int tid  = threadIdx.x;
    const int wave = tid >> 6, lane = tid & 63;
    const int l16  = lane & 15, kgl = lane >> 4;
    const int wrow = (wave & 1) * 16, wcol = (wave >> 1) * 32;

    __shared__ __align__(16) unsigned short As[32 * 32];
    __shared__ __align__(16) unsigned short Bs[64 * 32];

    f32x4 acc[2] = {};

    const int sa_m = tid & 31, sa_kg = (tid >> 5) & 3;  // used by tid<128
    const int sb_n = tid & 63, sb_kg = tid >> 6;

    const float* Ap = ns + ((size_t)(mt * 32 + sa_m) * Usz + u) * Nsz + sa_kg * 8;
    const float* Bp = Wout + (size_t)u * Nsz * Osz + (size_t)(sb_kg * 8) * Osz + ot * 64 + sb_n;

    float areg[8], breg[8];
    auto loadA = [&](int kb) {
        if (tid < 128) {
            const f32x4 v0 = *(const f32x4*)(Ap + kb);
            const f32x4 v1 = *(const f32x4*)(Ap + kb + 4);
            #pragma unroll
            for (int i = 0; i < 4; i++) { areg[i] = v0[i]; areg[4 + i] = v1[i]; }
        }
    };
    auto loadB = [&](int kb) {
        const float* p = Bp + (size_t)kb * Osz;
        #pragma unroll
        for (int j = 0; j < 8; j++) breg[j] = p[(size_t)j * Osz];
    };

    loadA(0); loadB(0);
    const int wa_off = ((sa_m >> 4) * 4 + sa_kg) * 128 + (sa_m & 15) * 8;
    const int wb_off = ((sb_n >> 4) * 4 + sb_kg) * 128 + (sb_n & 15) * 8;

    for (int step = 0; step < 32; ++step) {
        const int kb = step * 32;
        bf16x8 av = pack8(areg, 1.f);
        const bf16x8 bv = pack8(breg, 1.f);
        __syncthreads();
        if (tid < 128) *(bf16x8*)&As[wa_off] = av;
        *(bf16x8*)&Bs[wb_off] = bv;
        __syncthreads();
        if (step + 1 < 32) { loadA(kb + 32); loadB(kb + 32); }
        const bf16x8 afr = *(const bf16x8*)&As[(((wave & 1) * 4 + kgl) * 16 + l16) * 8];
        bf16x8 bfr[2];
        #pragma unroll
        for (int ni = 0; ni < 2; ni++)
            bfr[ni] = *(const bf16x8*)&Bs[((((wcol >> 4) + ni) * 4 + kgl) * 16 + l16) * 8];
        #pragma unroll
        for (int ni = 0; ni < 2; ni++)
            acc[ni] = __builtin_amdgcn_mfma_f32_16x16x32_bf16(afr, bfr[ni], acc[ni], 0, 0, 0);
    }

    #pragma unroll
    for (int ni = 0; ni < 2; ni++) {
        const int gcol = ot * 64 + wcol + ni * 16 + l16;
        #pragma unroll
        for (int rg = 0; rg < 4; rg++) {
            const int grow = mt * 32 + wrow + kgl * 4 + rg;
            out1[((size_t)grow * Usz + u) * Osz + gcol] = acc[ni][rg];
        }
    }
}

extern "C" void kernel_launch(void* const* d_in, const int* in_sizes, int n_in,
                              void* d_out, int out_size, void* d_ws, size_t ws_size,
                              hipStream_t stream)
{
    (void)in_sizes; (void)n_in; (void)out_size; (void)ws_size;
    const float* X     = (const float*)d_in[0];
    const float* state = (const float*)d_in[1];
    const float* W     = (const float*)d_in[2];
    const float* Win   = (const float*)d_in[3];
    const float* bias  = (const float*)d_in[4];
    const float* Wout  = (const float*)d_in[5];
    const float* sr    = (const float*)d_in[6];
    const float* alr   = (const float*)d_in[7];
    const float* temp  = (const float*)d_in[8];

    float* out0 = (float*)d_out;                      // (B,U,N)
    float* out1 = out0 + (size_t)Bsz * Usz * Nsz;     // (B,U,O)
    float* lr   = (float*)d_ws;                       // (B,U) f32, 8 KB

    lr_kernel<<<Bsz, 256, 0, stream>>>(X, alr, temp, lr);
    state_mfma<<<512, 256, 0, stream>>>(X, state, W, Win, bias, sr, lr, out0);
    out_mfma<<<256, 256, 0, stream>>>(out0, Wout, out1);
}